// Round 7
// baseline (300.911 us; speedup 1.0000x reference)
//
#include <hip/hip_runtime.h>
#include <math.h>

#define B_  4
#define V_  256
#define C1_ 64
#define C2_ 32
#define H0_ 128
#define H2_ 256

typedef short bf16x8 __attribute__((ext_vector_type(8)));
typedef float f32x4  __attribute__((ext_vector_type(4)));

static __device__ __forceinline__ short f2bf(float f) {
    unsigned u = __float_as_uint(f);
    u += 0x7fffu + ((u >> 16) & 1u);          // RNE
    return (short)(u >> 16);
}

// ---------------------------------------------------------------------------
// Weight prep body: transpose + bf16-convert W1c ([32][H0]->[H0][32]) and
// W2 ([H0][H0]->[H0][H0]^T) for both conv layers.
// Layout in wsW (shorts): W1cT1[128*32] | W2T1[128*128] | W1cT2 | W2T2
// ---------------------------------------------------------------------------
static __device__ __forceinline__ void prep_body(
    int idx, const float* __restrict__ W1c1, const float* __restrict__ W21,
    const float* __restrict__ W1c2, const float* __restrict__ W22,
    short* __restrict__ wsW)
{
    if (idx < 4096) {
        int n = idx >> 5, k = idx & 31;
        wsW[idx] = f2bf(W1c1[k * H0_ + n]);
    } else if (idx < 20480) {
        int t = idx - 4096; int n = t >> 7, k = t & 127;
        wsW[idx] = f2bf(W21[k * H0_ + n]);
    } else if (idx < 24576) {
        int t = idx - 20480; int n = t >> 5, k = t & 31;
        wsW[idx] = f2bf(W1c2[k * H0_ + n]);
    } else if (idx < 40960) {
        int t = idx - 24576; int n = t >> 7, k = t & 127;
        wsW[idx] = f2bf(W22[k * H0_ + n]);
    }
}

// ---------------------------------------------------------------------------
// Node hoist, 2 nodes per 256-thread block (for conv1's P,Q from xf).
// Halves run the original per-node loop -> bit-exact.
// ---------------------------------------------------------------------------
template <int CIN>
static __device__ __forceinline__ void npre_body(
    int node0, const float* __restrict__ x, const float* __restrict__ W1,
    const float* __restrict__ b1, float* __restrict__ P, float* __restrict__ Q,
    float* __restrict__ sx2)
{
    const int tid  = threadIdx.x;
    const int half = tid >> 7;
    const int n    = tid & 127;
    const int bi   = node0 + half;
    float* sx = sx2 + half * CIN;
    if (n < CIN) sx[n] = x[bi * CIN + n];
    __syncthreads();
    float accP = b1[n], accQ = 0.f;
    #pragma unroll 4
    for (int k = 0; k < CIN; k += 4) {
        float4 xv = *reinterpret_cast<const float4*>(&sx[k]);
        float wa0 = W1[(k + 0) * H0_ + n], wb0 = W1[(CIN + k + 0) * H0_ + n];
        float wa1 = W1[(k + 1) * H0_ + n], wb1 = W1[(CIN + k + 1) * H0_ + n];
        float wa2 = W1[(k + 2) * H0_ + n], wb2 = W1[(CIN + k + 2) * H0_ + n];
        float wa3 = W1[(k + 3) * H0_ + n], wb3 = W1[(CIN + k + 3) * H0_ + n];
        accP = fmaf(xv.x, wa0 - wb0, accP);  accQ = fmaf(xv.x, wb0, accQ);
        accP = fmaf(xv.y, wa1 - wb1, accP);  accQ = fmaf(xv.y, wb1, accQ);
        accP = fmaf(xv.z, wa2 - wb2, accP);  accQ = fmaf(xv.z, wb2, accQ);
        accP = fmaf(xv.w, wa3 - wb3, accP);  accQ = fmaf(xv.w, wb3, accQ);
    }
    P[bi * H0_ + n] = accP;
    Q[bi * H0_ + n] = accQ;
}

// ---------------------------------------------------------------------------
// Fused launch 1: blocks 0..159 = weight prep; blocks 160..671 = node hoist
// for conv1 (2 nodes/block).
// ---------------------------------------------------------------------------
__global__ __launch_bounds__(256) void pre1_fused_k(
    const float* __restrict__ W1c1, const float* __restrict__ W21,
    const float* __restrict__ W1c2, const float* __restrict__ W22,
    short* __restrict__ wsW,
    const float* __restrict__ xf, const float* __restrict__ ec1W1,
    const float* __restrict__ ec1b1, float* __restrict__ P, float* __restrict__ Q)
{
    if (blockIdx.x < 160) {
        prep_body(blockIdx.x * 256 + threadIdx.x, W1c1, W21, W1c2, W22, wsW);
    } else {
        __shared__ __align__(16) float sx2[2 * C1_];
        npre_body<C1_>((blockIdx.x - 160) * 2, xf, ec1W1, ec1b1, P, Q, sx2);
    }
}

// ---------------------------------------------------------------------------
// EdgeConvE core (R3 body). Instead of writing the output row to global, it
// leaves the node's full H0 row in s_x (zeros for isolated nodes). The
// caller syncs and runs a per-node tail that consumes s_x.
// ---------------------------------------------------------------------------
static __device__ void conv_core(
    const int bi, const int* __restrict__ adj, const float* __restrict__ e,
    const float* __restrict__ P, const float* __restrict__ Q,
    const short* __restrict__ W1cT, const short* __restrict__ W2T,
    const float* __restrict__ b2,
    int* __restrict__ s_list, int* __restrict__ s_wc, short (*s_h1)[136],
    float* __restrict__ s_x)
{
    const int b    = bi >> 8;
    const int tid  = threadIdx.x;
    const int w    = tid >> 6;
    const int lane = tid & 63;
    const int l15  = lane & 15;
    const int quad = lane >> 4;

    // ballot-based neighbor list (no atomics)
    const int av = adj[bi * V_ + tid];
    unsigned long long bm = __ballot(av > 0);
    if (lane == 0) s_wc[w] = __popcll(bm);
    __syncthreads();
    const int cnt = s_wc[0] + s_wc[1] + s_wc[2] + s_wc[3];
    if (av > 0) {
        int base = 0;
        #pragma unroll
        for (int k = 0; k < 4; ++k) if (k < w) base += s_wc[k];
        int pos = base + __popcll(bm & ((1ull << lane) - 1ull));
        s_list[pos] = tid;
    }
    __syncthreads();
    if (cnt == 0) { if (tid < H0_) s_x[tid] = 0.f; return; }   // isolated node

    // GEMM2 B-fragments: wave w owns N-tiles 2w, 2w+1 -> 8 frags (32 VGPR)
    bf16x8 B2[2][4];
    float bb[2], vmax[2];
    #pragma unroll
    for (int h = 0; h < 2; ++h) {
        const int nt = w * 2 + h;
        #pragma unroll
        for (int kk = 0; kk < 4; ++kk)
            B2[h][kk] = *(const bf16x8*)(W2T + (nt * 16 + l15) * H0_ + kk * 32 + quad * 8);
        bb[h]   = b2[nt * 16 + l15];
        vmax[h] = 0.f;
    }
    float Pp[8];
    #pragma unroll
    for (int nt = 0; nt < 8; ++nt) Pp[nt] = P[bi * H0_ + nt * 16 + l15];

    const int row0 = w * 16;

    // prefetch first pass's e rows
    int ta0 = row0 + l15; if (ta0 >= cnt) ta0 = cnt - 1;
    const float* er0 = e + (bi * V_ + s_list[ta0]) * C2_ + quad * 8;
    float4 e0 = *(const float4*)(er0);
    float4 e1 = *(const float4*)(er0 + 4);

    for (int t0 = 0; t0 < cnt; t0 += 64) {
        const int tb = t0 + row0;

        // A-fragment for GEMM1 from prefetched e: A[m=l15][k=quad*8+j]
        bf16x8 A1;
        A1[0] = f2bf(e0.x); A1[1] = f2bf(e0.y); A1[2] = f2bf(e0.z); A1[3] = f2bf(e0.w);
        A1[4] = f2bf(e1.x); A1[5] = f2bf(e1.y); A1[6] = f2bf(e1.z); A1[7] = f2bf(e1.w);

        // issue next pass's e loads now; they retire under GEMM1+GEMM2
        {
            int tn = t0 + 64 + row0 + l15; if (tn >= cnt) tn = cnt - 1;
            const float* ern = e + (bi * V_ + s_list[tn]) * C2_ + quad * 8;
            e0 = *(const float4*)(ern);
            e1 = *(const float4*)(ern + 4);
        }

        // GEMM1: e @ W1c (K=32, one MFMA per N-tile)
        f32x4 acc[8];
        #pragma unroll
        for (int nt = 0; nt < 8; ++nt) {
            bf16x8 B1 = *(const bf16x8*)(W1cT + (nt * 16 + l15) * C2_ + quad * 8);
            f32x4 z = {0.f, 0.f, 0.f, 0.f};
            acc[nt] = __builtin_amdgcn_mfma_f32_16x16x32_bf16(A1, B1, z, 0, 0, 0);
        }

        // make sure previous pass's GEMM2 readers are done before overwriting
        if (t0 > 0) __syncthreads();

        // epilogue 1: + P[i] + Q[j], relu, bf16 -> LDS (rows = edge slots)
        #pragma unroll
        for (int r = 0; r < 4; ++r) {
            int t = tb + quad * 4 + r; if (t >= cnt) t = cnt - 1;
            const float* Qr = Q + (b * V_ + s_list[t]) * H0_ + l15;
            short* dst = &s_h1[row0 + quad * 4 + r][l15];
            #pragma unroll
            for (int nt = 0; nt < 8; ++nt) {
                float v = acc[nt][r] + Pp[nt] + Qr[nt * 16];
                dst[nt * 16] = f2bf(fmaxf(v, 0.f));
            }
        }

        __syncthreads();

        // GEMM2: h1 @ W2, N-split across waves, M = all 64 edge rows
        #pragma unroll
        for (int mt = 0; mt < 4; ++mt) {
            f32x4 a20 = {0.f,0.f,0.f,0.f}, a21 = {0.f,0.f,0.f,0.f};
            #pragma unroll
            for (int kk = 0; kk < 4; ++kk) {
                bf16x8 A2 = *(const bf16x8*)(&s_h1[mt * 16 + l15][kk * 32 + quad * 8]);
                a20 = __builtin_amdgcn_mfma_f32_16x16x32_bf16(A2, B2[0][kk], a20, 0, 0, 0);
                a21 = __builtin_amdgcn_mfma_f32_16x16x32_bf16(A2, B2[1][kk], a21, 0, 0, 0);
            }
            float m0 = fmaxf(fmaxf(a20[0], a20[1]), fmaxf(a20[2], a20[3]));
            float m1 = fmaxf(fmaxf(a21[0], a21[1]), fmaxf(a21[2], a21[3]));
            vmax[0] = fmaxf(vmax[0], fmaxf(m0 + bb[0], 0.f));
            vmax[1] = fmaxf(vmax[1], fmaxf(m1 + bb[1], 0.f));
        }
    }

    // cross-quad (rows) max -> this wave's 32 channels into the LDS row
    #pragma unroll
    for (int h = 0; h < 2; ++h) {
        float p = vmax[h];
        p = fmaxf(p, __shfl_xor(p, 16, 64));
        p = fmaxf(p, __shfl_xor(p, 32, 64));
        if (quad == 0) s_x[(w * 2 + h) * 16 + l15] = p;
    }
}

// ---------------------------------------------------------------------------
// conv1 + node-hoist tail: block bi computes x1[bi] (LDS only), then
// P2[bi],Q2[bi] for conv2.  Per-output fma chains identical to npre_body
// -> bit-exact.  Threads 0-127 compute P, 128-255 compute Q.
// Writes go to FRESH buffers P2/Q2 (in-place would race other blocks'
// neighbor reads of Q).
// ---------------------------------------------------------------------------
__global__ __launch_bounds__(256, 4) void conv1_fused_k(
    const int* __restrict__ adj, const float* __restrict__ e,
    const float* __restrict__ P, const float* __restrict__ Q,
    const short* __restrict__ W1cT, const short* __restrict__ W2T,
    const float* __restrict__ b2,
    const float* __restrict__ W1n, const float* __restrict__ b1n,
    float* __restrict__ P2, float* __restrict__ Q2)
{
    const int bi = blockIdx.x;
    __shared__ int s_list[V_];
    __shared__ int s_wc[4];
    __shared__ __align__(16) short s_h1[64][136];
    __shared__ __align__(16) float s_x[H0_];

    conv_core(bi, adj, e, P, Q, W1cT, W2T, b2, s_list, s_wc, s_h1, s_x);
    __syncthreads();

    const int tid  = threadIdx.x;
    const int half = tid >> 7;
    const int n    = tid & 127;
    if (half == 0) {
        float accP = b1n[n];
        #pragma unroll 4
        for (int k = 0; k < H0_; k += 4) {
            float4 xv = *reinterpret_cast<const float4*>(&s_x[k]);
            float wa0 = W1n[(k + 0) * H0_ + n], wb0 = W1n[(H0_ + k + 0) * H0_ + n];
            float wa1 = W1n[(k + 1) * H0_ + n], wb1 = W1n[(H0_ + k + 1) * H0_ + n];
            float wa2 = W1n[(k + 2) * H0_ + n], wb2 = W1n[(H0_ + k + 2) * H0_ + n];
            float wa3 = W1n[(k + 3) * H0_ + n], wb3 = W1n[(H0_ + k + 3) * H0_ + n];
            accP = fmaf(xv.x, wa0 - wb0, accP);
            accP = fmaf(xv.y, wa1 - wb1, accP);
            accP = fmaf(xv.z, wa2 - wb2, accP);
            accP = fmaf(xv.w, wa3 - wb3, accP);
        }
        P2[bi * H0_ + n] = accP;
    } else {
        float accQ = 0.f;
        #pragma unroll 4
        for (int k = 0; k < H0_; k += 4) {
            float4 xv = *reinterpret_cast<const float4*>(&s_x[k]);
            float wb0 = W1n[(H0_ + k + 0) * H0_ + n];
            float wb1 = W1n[(H0_ + k + 1) * H0_ + n];
            float wb2 = W1n[(H0_ + k + 2) * H0_ + n];
            float wb3 = W1n[(H0_ + k + 3) * H0_ + n];
            accQ = fmaf(xv.x, wb0, accQ);
            accQ = fmaf(xv.y, wb1, accQ);
            accQ = fmaf(xv.z, wb2, accQ);
            accQ = fmaf(xv.w, wb3, accQ);
        }
        Q2[bi * H0_ + n] = accQ;
    }
}

// ---------------------------------------------------------------------------
// conv2 + pair-hoist tail: block bi computes x2[bi] (LDS only), then
// Ai[bi] = x2@W3[H0:]+b3 and Aj[bi] = x2@W3[:H0].  Chains identical to the
// original pair_pre kernel -> bit-exact.
// ---------------------------------------------------------------------------
__global__ __launch_bounds__(256, 4) void conv2_fused_k(
    const int* __restrict__ adj, const float* __restrict__ e,
    const float* __restrict__ P, const float* __restrict__ Q,
    const short* __restrict__ W1cT, const short* __restrict__ W2T,
    const float* __restrict__ b2,
    const float* __restrict__ W3, const float* __restrict__ b3,
    float* __restrict__ Ai, float* __restrict__ Aj)
{
    const int bi = blockIdx.x;
    __shared__ int s_list[V_];
    __shared__ int s_wc[4];
    __shared__ __align__(16) short s_h1[64][136];
    __shared__ __align__(16) float s_x[H0_];

    conv_core(bi, adj, e, P, Q, W1cT, W2T, b2, s_list, s_wc, s_h1, s_x);
    __syncthreads();

    const int n = threadIdx.x;                 // 256 output columns
    float aI = b3[n], aJ = 0.f;
    #pragma unroll 4
    for (int k = 0; k < H0_; k += 4) {
        float4 xv = *reinterpret_cast<const float4*>(&s_x[k]);
        aJ = fmaf(xv.x, W3[(k + 0) * H2_ + n], aJ);
        aJ = fmaf(xv.y, W3[(k + 1) * H2_ + n], aJ);
        aJ = fmaf(xv.z, W3[(k + 2) * H2_ + n], aJ);
        aJ = fmaf(xv.w, W3[(k + 3) * H2_ + n], aJ);
        aI = fmaf(xv.x, W3[(H0_ + k + 0) * H2_ + n], aI);
        aI = fmaf(xv.y, W3[(H0_ + k + 1) * H2_ + n], aI);
        aI = fmaf(xv.z, W3[(H0_ + k + 2) * H2_ + n], aI);
        aI = fmaf(xv.w, W3[(H0_ + k + 3) * H2_ + n], aI);
    }
    Ai[bi * H2_ + n] = aI;
    Aj[bi * H2_ + n] = aJ;
}

// ---------------------------------------------------------------------------
// Pair output — byte-identical to R3: 2048 blocks, Aj tile staged in LDS
// with float4 XOR swizzle.
// ---------------------------------------------------------------------------
__global__ __launch_bounds__(256) void pair_out_k(
    const float* __restrict__ Ai, const float* __restrict__ Aj,
    const float* __restrict__ Wo, const float* __restrict__ bo,
    float* __restrict__ out)
{
    const int blk  = blockIdx.x;                       // 2048 blocks
    const int b    = blk >> 9;
    const int ig   = (blk >> 3) & 63;
    const int jq   = blk & 7;                          // 8 tiles of 32 j
    const int i    = (ig << 2) + (threadIdx.x >> 6);
    const int lane = threadIdx.x & 63;
    const int jj   = lane >> 4;
    const int c    = lane & 15;

    __shared__ __align__(16) float4 s_aj[32 * 64];     // 32 KB, swizzled

    // cooperative stage: 32 rows x 64 float4 (coalesced; write = row-perm)
    const float4* src = (const float4*)(Aj + (b * V_ + jq * 32) * H2_);
    #pragma unroll
    for (int k = 0; k < 8; ++k) {
        int g  = threadIdx.x + k * 256;
        int jr = g >> 6, f = g & 63;
        s_aj[jr * 64 + (f ^ (jr & 7))] = src[g];
    }

    const float* ai = Ai + (b * V_ + i) * H2_ + c * 16;
    float4 a0 = *(const float4*)(ai);
    float4 a1 = *(const float4*)(ai + 4);
    float4 a2 = *(const float4*)(ai + 8);
    float4 a3 = *(const float4*)(ai + 12);
    const float* wo = Wo + c * 16;
    float4 w0 = *(const float4*)(wo);
    float4 w1 = *(const float4*)(wo + 4);
    float4 w2 = *(const float4*)(wo + 8);
    float4 w3 = *(const float4*)(wo + 12);
    const float bo0 = bo[0];

    __syncthreads();

    for (int js = 0; js < 32; js += 4) {
        const int jr = js + jj;
        const float4* arow = &s_aj[jr * 64];
        const int sw = jr & 7, f0 = c * 4;
        float4 q0 = arow[(f0 + 0) ^ sw];
        float4 q1 = arow[(f0 + 1) ^ sw];
        float4 q2 = arow[(f0 + 2) ^ sw];
        float4 q3 = arow[(f0 + 3) ^ sw];
        float p;
        p = fmaxf(a0.x + q0.x, 0.f) * w0.x;
        p = fmaf(fmaxf(a0.y + q0.y, 0.f), w0.y, p);
        p = fmaf(fmaxf(a0.z + q0.z, 0.f), w0.z, p);
        p = fmaf(fmaxf(a0.w + q0.w, 0.f), w0.w, p);
        p = fmaf(fmaxf(a1.x + q1.x, 0.f), w1.x, p);
        p = fmaf(fmaxf(a1.y + q1.y, 0.f), w1.y, p);
        p = fmaf(fmaxf(a1.z + q1.z, 0.f), w1.z, p);
        p = fmaf(fmaxf(a1.w + q1.w, 0.f), w1.w, p);
        p = fmaf(fmaxf(a2.x + q2.x, 0.f), w2.x, p);
        p = fmaf(fmaxf(a2.y + q2.y, 0.f), w2.y, p);
        p = fmaf(fmaxf(a2.z + q2.z, 0.f), w2.z, p);
        p = fmaf(fmaxf(a2.w + q2.w, 0.f), w2.w, p);
        p = fmaf(fmaxf(a3.x + q3.x, 0.f), w3.x, p);
        p = fmaf(fmaxf(a3.y + q3.y, 0.f), w3.y, p);
        p = fmaf(fmaxf(a3.z + q3.z, 0.f), w3.z, p);
        p = fmaf(fmaxf(a3.w + q3.w, 0.f), w3.w, p);
        #pragma unroll
        for (int off = 1; off < 16; off <<= 1)
            p += __shfl_xor(p, off, 64);               // stays within jj group
        if (c == 0)
            out[(b * V_ + i) * V_ + jq * 32 + jr] =
                1.f / (1.f + __builtin_expf(-(p + bo0)));
    }
}

// ---------------------------------------------------------------------------
extern "C" void kernel_launch(void* const* d_in, const int* in_sizes, int n_in,
                              void* d_out, int out_size, void* d_ws, size_t ws_size,
                              hipStream_t stream) {
    const int*   adj   = (const int*)  d_in[0];
    const float* xf    = (const float*)d_in[1];
    const float* ea    = (const float*)d_in[2];
    const float* ec1W1 = (const float*)d_in[3];
    const float* ec1b1 = (const float*)d_in[4];
    const float* ec1W2 = (const float*)d_in[5];
    const float* ec1b2 = (const float*)d_in[6];
    const float* ec2W1 = (const float*)d_in[7];
    const float* ec2b1 = (const float*)d_in[8];
    const float* ec2W2 = (const float*)d_in[9];
    const float* ec2b2 = (const float*)d_in[10];
    const float* h3W   = (const float*)d_in[11];
    const float* h3b   = (const float*)d_in[12];
    const float* oW    = (const float*)d_in[13];
    const float* ob    = (const float*)d_in[14];
    float* out = (float*)d_out;

    const int NV = B_ * V_;                    // 1024 nodes
    float* P  = (float*)d_ws;                  // NV*H0  (conv1 hoist)
    float* Q  = P  + NV * H0_;                 // NV*H0
    float* P2 = Q  + NV * H0_;                 // NV*H0  (conv2 hoist)
    float* Q2 = P2 + NV * H0_;                 // NV*H0
    float* Ai = Q2 + NV * H0_;                 // NV*H2
    float* Aj = Ai + NV * H2_;                 // NV*H2
    short* wsW = (short*)(Aj + NV * H2_);      // 40960 bf16 weights
    short* W1cT1 = wsW;
    short* W2T1  = wsW + 4096;
    short* W1cT2 = wsW + 20480;
    short* W2T2  = wsW + 24576;

    // launch 1: weight prep (160 blocks) || node hoist conv1 (512 blocks)
    pre1_fused_k<<<672, 256, 0, stream>>>(ec1W1 + 2 * C1_ * H0_, ec1W2,
                                          ec2W1 + 2 * H0_ * H0_, ec2W2, wsW,
                                          xf, ec1W1, ec1b1, P, Q);
    // launch 2: conv1 + node-hoist tail (writes P2,Q2)
    conv1_fused_k<<<NV, 256, 0, stream>>>(adj, ea, P, Q, W1cT1, W2T1, ec1b2,
                                          ec2W1, ec2b1, P2, Q2);
    // launch 3: conv2 + pair-hoist tail (writes Ai,Aj)
    conv2_fused_k<<<NV, 256, 0, stream>>>(adj, ea, P2, Q2, W1cT2, W2T2, ec2b2,
                                          h3W, h3b, Ai, Aj);
    // launch 4: pair output
    pair_out_k<<<2048, 256, 0, stream>>>(Ai, Aj, oW, ob, out);
}

// Round 8
// 262.948 us; speedup vs baseline: 1.1444x; 1.1444x over previous
//
#include <hip/hip_runtime.h>
#include <math.h>

#define B_  4
#define V_  256
#define C1_ 64
#define C2_ 32
#define H0_ 128
#define H2_ 256

typedef short bf16x8 __attribute__((ext_vector_type(8)));
typedef float f32x4  __attribute__((ext_vector_type(4)));

static __device__ __forceinline__ short f2bf(float f) {
    unsigned u = __float_as_uint(f);
    u += 0x7fffu + ((u >> 16) & 1u);          // RNE
    return (short)(u >> 16);
}

// ---------------------------------------------------------------------------
// Weight prep body: transpose + bf16-convert W1c ([32][H0]->[H0][32]) and
// W2 ([H0][H0]->[H0][H0]^T) for both conv layers.
// Layout in wsW (shorts): W1cT1[128*32] | W2T1[128*128] | W1cT2 | W2T2
// ---------------------------------------------------------------------------
static __device__ __forceinline__ void prep_body(
    int idx, const float* __restrict__ W1c1, const float* __restrict__ W21,
    const float* __restrict__ W1c2, const float* __restrict__ W22,
    short* __restrict__ wsW)
{
    if (idx < 4096) {
        int n = idx >> 5, k = idx & 31;
        wsW[idx] = f2bf(W1c1[k * H0_ + n]);
    } else if (idx < 20480) {
        int t = idx - 4096; int n = t >> 7, k = t & 127;
        wsW[idx] = f2bf(W21[k * H0_ + n]);
    } else if (idx < 24576) {
        int t = idx - 20480; int n = t >> 5, k = t & 31;
        wsW[idx] = f2bf(W1c2[k * H0_ + n]);
    } else if (idx < 40960) {
        int t = idx - 24576; int n = t >> 7, k = t & 127;
        wsW[idx] = f2bf(W22[k * H0_ + n]);
    }
}

// ---------------------------------------------------------------------------
// Node hoist, 2 nodes per 256-thread block: halves are independent
// 128-thread groups running the ORIGINAL per-node loop -> bit-exact,
// W1 streamed once per block serves 2 nodes, 512 blocks keeps coverage.
// (Kept as a SEPARATE kernel: R7 proved fusing weight-streaming tails into
// conv thrashes L2 against the e-stream -> 106 MB HBM refetch.)
// ---------------------------------------------------------------------------
template <int CIN>
static __device__ __forceinline__ void npre_body(
    int node0, const float* __restrict__ x, const float* __restrict__ W1,
    const float* __restrict__ b1, float* __restrict__ P, float* __restrict__ Q,
    float* __restrict__ sx2)
{
    const int tid  = threadIdx.x;
    const int half = tid >> 7;
    const int n    = tid & 127;
    const int bi   = node0 + half;
    float* sx = sx2 + half * CIN;
    if (n < CIN) sx[n] = x[bi * CIN + n];
    __syncthreads();
    float accP = b1[n], accQ = 0.f;
    #pragma unroll 4
    for (int k = 0; k < CIN; k += 4) {
        float4 xv = *reinterpret_cast<const float4*>(&sx[k]);
        float wa0 = W1[(k + 0) * H0_ + n], wb0 = W1[(CIN + k + 0) * H0_ + n];
        float wa1 = W1[(k + 1) * H0_ + n], wb1 = W1[(CIN + k + 1) * H0_ + n];
        float wa2 = W1[(k + 2) * H0_ + n], wb2 = W1[(CIN + k + 2) * H0_ + n];
        float wa3 = W1[(k + 3) * H0_ + n], wb3 = W1[(CIN + k + 3) * H0_ + n];
        accP = fmaf(xv.x, wa0 - wb0, accP);  accQ = fmaf(xv.x, wb0, accQ);
        accP = fmaf(xv.y, wa1 - wb1, accP);  accQ = fmaf(xv.y, wb1, accQ);
        accP = fmaf(xv.z, wa2 - wb2, accP);  accQ = fmaf(xv.z, wb2, accQ);
        accP = fmaf(xv.w, wa3 - wb3, accP);  accQ = fmaf(xv.w, wb3, accQ);
    }
    P[bi * H0_ + n] = accP;
    Q[bi * H0_ + n] = accQ;
}

// ---------------------------------------------------------------------------
// Fused launch 1: blocks 0..159 = weight prep; blocks 160..671 = node hoist
// for conv1 (2 nodes/block).  Independent inputs/outputs.
// ---------------------------------------------------------------------------
__global__ __launch_bounds__(256) void pre1_fused_k(
    const float* __restrict__ W1c1, const float* __restrict__ W21,
    const float* __restrict__ W1c2, const float* __restrict__ W22,
    short* __restrict__ wsW,
    const float* __restrict__ xf, const float* __restrict__ ec1W1,
    const float* __restrict__ ec1b1, float* __restrict__ P, float* __restrict__ Q)
{
    if (blockIdx.x < 160) {
        prep_body(blockIdx.x * 256 + threadIdx.x, W1c1, W21, W1c2, W22, wsW);
    } else {
        __shared__ __align__(16) float sx2[2 * C1_];
        npre_body<C1_>((blockIdx.x - 160) * 2, xf, ec1W1, ec1b1, P, Q, sx2);
    }
}

// standalone 2-node node_pre for conv2 (CIN=128), grid 512
template <int CIN>
__global__ __launch_bounds__(256) void npre2_k(
    const float* __restrict__ x, const float* __restrict__ W1,
    const float* __restrict__ b1, float* __restrict__ P, float* __restrict__ Q)
{
    __shared__ __align__(16) float sx2[2 * CIN];
    npre_body<CIN>(blockIdx.x * 2, x, W1, b1, P, Q, sx2);
}

// ---------------------------------------------------------------------------
// EdgeConvE main — R6 body, but __launch_bounds__(256, 8):
// R7 measured the core (+ even a fused fp32 tail) at 64 VGPR, and LDS is
// 19.0 KB -> 8 blocks/CU fits both budgets (8 waves/SIMD @ 64 VGPR;
// 8 x 19 KB = 152 KB <= 160 KB).  The kernel is latency-bound (low MfmaUtil
// and VALUBusy), so doubling the resident-wave pool should cut exposed
// e-load / Q-gather / barrier latency.
// ---------------------------------------------------------------------------
__global__ __launch_bounds__(256, 8) void conv_mfma_k(
    const int* __restrict__ adj, const float* __restrict__ e,
    const float* __restrict__ P, const float* __restrict__ Q,
    const short* __restrict__ W1cT, const short* __restrict__ W2T,
    const float* __restrict__ b2, float* __restrict__ out)
{
    const int bi   = blockIdx.x;           // b*V + i
    const int b    = bi >> 8;
    const int tid  = threadIdx.x;
    const int w    = tid >> 6;
    const int lane = tid & 63;
    const int l15  = lane & 15;
    const int quad = lane >> 4;

    __shared__ int s_list[V_];
    __shared__ int s_wc[4];
    __shared__ __align__(16) short s_h1[64][136];   // 272 B stride, 16B-aligned

    // ballot-based neighbor list (no atomics)
    const int av = adj[bi * V_ + tid];
    unsigned long long bm = __ballot(av > 0);
    if (lane == 0) s_wc[w] = __popcll(bm);
    __syncthreads();
    const int cnt = s_wc[0] + s_wc[1] + s_wc[2] + s_wc[3];
    if (av > 0) {
        int base = 0;
        #pragma unroll
        for (int k = 0; k < 4; ++k) if (k < w) base += s_wc[k];
        int pos = base + __popcll(bm & ((1ull << lane) - 1ull));
        s_list[pos] = tid;
    }
    __syncthreads();
    if (cnt == 0) { if (tid < H0_) out[bi * H0_ + tid] = 0.f; return; }

    // GEMM2 B-fragments: wave w owns N-tiles 2w, 2w+1 -> 8 frags (32 VGPR)
    bf16x8 B2[2][4];
    float bb[2], vmax[2];
    #pragma unroll
    for (int h = 0; h < 2; ++h) {
        const int nt = w * 2 + h;
        #pragma unroll
        for (int kk = 0; kk < 4; ++kk)
            B2[h][kk] = *(const bf16x8*)(W2T + (nt * 16 + l15) * H0_ + kk * 32 + quad * 8);
        bb[h]   = b2[nt * 16 + l15];
        vmax[h] = 0.f;
    }
    float Pp[8];
    #pragma unroll
    for (int nt = 0; nt < 8; ++nt) Pp[nt] = P[bi * H0_ + nt * 16 + l15];

    const int row0 = w * 16;

    // prefetch first pass's e rows
    int ta0 = row0 + l15; if (ta0 >= cnt) ta0 = cnt - 1;
    const float* er0 = e + (bi * V_ + s_list[ta0]) * C2_ + quad * 8;
    float4 e0 = *(const float4*)(er0);
    float4 e1 = *(const float4*)(er0 + 4);

    for (int t0 = 0; t0 < cnt; t0 += 64) {
        const int tb = t0 + row0;

        // A-fragment for GEMM1 from prefetched e: A[m=l15][k=quad*8+j]
        bf16x8 A1;
        A1[0] = f2bf(e0.x); A1[1] = f2bf(e0.y); A1[2] = f2bf(e0.z); A1[3] = f2bf(e0.w);
        A1[4] = f2bf(e1.x); A1[5] = f2bf(e1.y); A1[6] = f2bf(e1.z); A1[7] = f2bf(e1.w);

        // issue next pass's e loads now; they retire under GEMM1+GEMM2
        {
            int tn = t0 + 64 + row0 + l15; if (tn >= cnt) tn = cnt - 1;
            const float* ern = e + (bi * V_ + s_list[tn]) * C2_ + quad * 8;
            e0 = *(const float4*)(ern);
            e1 = *(const float4*)(ern + 4);
        }

        // GEMM1: e @ W1c (K=32, one MFMA per N-tile; B1 from L1-resident global)
        f32x4 acc[8];
        #pragma unroll
        for (int nt = 0; nt < 8; ++nt) {
            bf16x8 B1 = *(const bf16x8*)(W1cT + (nt * 16 + l15) * C2_ + quad * 8);
            f32x4 z = {0.f, 0.f, 0.f, 0.f};
            acc[nt] = __builtin_amdgcn_mfma_f32_16x16x32_bf16(A1, B1, z, 0, 0, 0);
        }

        // make sure previous pass's GEMM2 readers are done before overwriting
        if (t0 > 0) __syncthreads();

        // epilogue 1: + P[i] + Q[j], relu, bf16 -> LDS (rows = edge slots)
        #pragma unroll
        for (int r = 0; r < 4; ++r) {
            int t = tb + quad * 4 + r; if (t >= cnt) t = cnt - 1;
            const float* Qr = Q + (b * V_ + s_list[t]) * H0_ + l15;
            short* dst = &s_h1[row0 + quad * 4 + r][l15];
            #pragma unroll
            for (int nt = 0; nt < 8; ++nt) {
                float v = acc[nt][r] + Pp[nt] + Qr[nt * 16];
                dst[nt * 16] = f2bf(fmaxf(v, 0.f));
            }
        }

        __syncthreads();

        // GEMM2: h1 @ W2, N-split across waves, M = all 64 edge rows
        #pragma unroll
        for (int mt = 0; mt < 4; ++mt) {
            f32x4 a20 = {0.f,0.f,0.f,0.f}, a21 = {0.f,0.f,0.f,0.f};
            #pragma unroll
            for (int kk = 0; kk < 4; ++kk) {
                bf16x8 A2 = *(const bf16x8*)(&s_h1[mt * 16 + l15][kk * 32 + quad * 8]);
                a20 = __builtin_amdgcn_mfma_f32_16x16x32_bf16(A2, B2[0][kk], a20, 0, 0, 0);
                a21 = __builtin_amdgcn_mfma_f32_16x16x32_bf16(A2, B2[1][kk], a21, 0, 0, 0);
            }
            float m0 = fmaxf(fmaxf(a20[0], a20[1]), fmaxf(a20[2], a20[3]));
            float m1 = fmaxf(fmaxf(a21[0], a21[1]), fmaxf(a21[2], a21[3]));
            vmax[0] = fmaxf(vmax[0], fmaxf(m0 + bb[0], 0.f));
            vmax[1] = fmaxf(vmax[1], fmaxf(m1 + bb[1], 0.f));
        }
    }

    // cross-quad (rows) max, then direct write of this wave's own channels
    #pragma unroll
    for (int h = 0; h < 2; ++h) {
        float p = vmax[h];
        p = fmaxf(p, __shfl_xor(p, 16, 64));
        p = fmaxf(p, __shfl_xor(p, 32, 64));
        if (quad == 0) out[bi * H0_ + (w * 2 + h) * 16 + l15] = p;
    }
}

// ---------------------------------------------------------------------------
// Pair hoist, 2 nodes per 256-thread block: thread n computes BOTH nodes'
// column-n outputs, sharing one W3 stream.  Bit-exact per-node fma order.
// ---------------------------------------------------------------------------
__global__ __launch_bounds__(256) void ppre2_k(
    const float* __restrict__ x2, const float* __restrict__ W3,
    const float* __restrict__ b3, float* __restrict__ Ai, float* __restrict__ Aj)
{
    const int nb = blockIdx.x;         // 512 blocks, 2 nodes each
    const int n  = threadIdx.x;        // 256
    __shared__ __align__(16) float s_x[2 * H0_];
    s_x[n] = x2[nb * 2 * H0_ + n];
    __syncthreads();
    const float bv = b3[n];
    float aI0 = bv, aJ0 = 0.f, aI1 = bv, aJ1 = 0.f;
    #pragma unroll 4
    for (int k = 0; k < H0_; k += 4) {
        float4 x0 = *reinterpret_cast<const float4*>(&s_x[k]);
        float4 x1 = *reinterpret_cast<const float4*>(&s_x[H0_ + k]);
        float wj0 = W3[(k + 0) * H2_ + n];
        float wj1 = W3[(k + 1) * H2_ + n];
        float wj2 = W3[(k + 2) * H2_ + n];
        float wj3 = W3[(k + 3) * H2_ + n];
        float wi0 = W3[(H0_ + k + 0) * H2_ + n];
        float wi1 = W3[(H0_ + k + 1) * H2_ + n];
        float wi2 = W3[(H0_ + k + 2) * H2_ + n];
        float wi3 = W3[(H0_ + k + 3) * H2_ + n];
        aJ0 = fmaf(x0.x, wj0, aJ0); aJ0 = fmaf(x0.y, wj1, aJ0);
        aJ0 = fmaf(x0.z, wj2, aJ0); aJ0 = fmaf(x0.w, wj3, aJ0);
        aI0 = fmaf(x0.x, wi0, aI0); aI0 = fmaf(x0.y, wi1, aI0);
        aI0 = fmaf(x0.z, wi2, aI0); aI0 = fmaf(x0.w, wi3, aI0);
        aJ1 = fmaf(x1.x, wj0, aJ1); aJ1 = fmaf(x1.y, wj1, aJ1);
        aJ1 = fmaf(x1.z, wj2, aJ1); aJ1 = fmaf(x1.w, wj3, aJ1);
        aI1 = fmaf(x1.x, wi0, aI1); aI1 = fmaf(x1.y, wi1, aI1);
        aI1 = fmaf(x1.z, wi2, aI1); aI1 = fmaf(x1.w, wi3, aI1);
    }
    const int r0 = nb * 2;
    Ai[r0 * H2_ + n]       = aI0;
    Aj[r0 * H2_ + n]       = aJ0;
    Ai[(r0 + 1) * H2_ + n] = aI1;
    Aj[(r0 + 1) * H2_ + n] = aJ1;
}

// ---------------------------------------------------------------------------
// Pair output — byte-identical to R3/R6: 2048 blocks, Aj tile staged in LDS
// with float4 XOR swizzle.
// ---------------------------------------------------------------------------
__global__ __launch_bounds__(256) void pair_out_k(
    const float* __restrict__ Ai, const float* __restrict__ Aj,
    const float* __restrict__ Wo, const float* __restrict__ bo,
    float* __restrict__ out)
{
    const int blk  = blockIdx.x;                       // 2048 blocks
    const int b    = blk >> 9;
    const int ig   = (blk >> 3) & 63;
    const int jq   = blk & 7;                          // 8 tiles of 32 j
    const int i    = (ig << 2) + (threadIdx.x >> 6);
    const int lane = threadIdx.x & 63;
    const int jj   = lane >> 4;
    const int c    = lane & 15;

    __shared__ __align__(16) float4 s_aj[32 * 64];     // 32 KB, swizzled

    // cooperative stage: 32 rows x 64 float4 (coalesced; write = row-perm)
    const float4* src = (const float4*)(Aj + (b * V_ + jq * 32) * H2_);
    #pragma unroll
    for (int k = 0; k < 8; ++k) {
        int g  = threadIdx.x + k * 256;
        int jr = g >> 6, f = g & 63;
        s_aj[jr * 64 + (f ^ (jr & 7))] = src[g];
    }

    const float* ai = Ai + (b * V_ + i) * H2_ + c * 16;
    float4 a0 = *(const float4*)(ai);
    float4 a1 = *(const float4*)(ai + 4);
    float4 a2 = *(const float4*)(ai + 8);
    float4 a3 = *(const float4*)(ai + 12);
    const float* wo = Wo + c * 16;
    float4 w0 = *(const float4*)(wo);
    float4 w1 = *(const float4*)(wo + 4);
    float4 w2 = *(const float4*)(wo + 8);
    float4 w3 = *(const float4*)(wo + 12);
    const float bo0 = bo[0];

    __syncthreads();

    for (int js = 0; js < 32; js += 4) {
        const int jr = js + jj;
        const float4* arow = &s_aj[jr * 64];
        const int sw = jr & 7, f0 = c * 4;
        float4 q0 = arow[(f0 + 0) ^ sw];
        float4 q1 = arow[(f0 + 1) ^ sw];
        float4 q2 = arow[(f0 + 2) ^ sw];
        float4 q3 = arow[(f0 + 3) ^ sw];
        float p;
        p = fmaxf(a0.x + q0.x, 0.f) * w0.x;
        p = fmaf(fmaxf(a0.y + q0.y, 0.f), w0.y, p);
        p = fmaf(fmaxf(a0.z + q0.z, 0.f), w0.z, p);
        p = fmaf(fmaxf(a0.w + q0.w, 0.f), w0.w, p);
        p = fmaf(fmaxf(a1.x + q1.x, 0.f), w1.x, p);
        p = fmaf(fmaxf(a1.y + q1.y, 0.f), w1.y, p);
        p = fmaf(fmaxf(a1.z + q1.z, 0.f), w1.z, p);
        p = fmaf(fmaxf(a1.w + q1.w, 0.f), w1.w, p);
        p = fmaf(fmaxf(a2.x + q2.x, 0.f), w2.x, p);
        p = fmaf(fmaxf(a2.y + q2.y, 0.f), w2.y, p);
        p = fmaf(fmaxf(a2.z + q2.z, 0.f), w2.z, p);
        p = fmaf(fmaxf(a2.w + q2.w, 0.f), w2.w, p);
        p = fmaf(fmaxf(a3.x + q3.x, 0.f), w3.x, p);
        p = fmaf(fmaxf(a3.y + q3.y, 0.f), w3.y, p);
        p = fmaf(fmaxf(a3.z + q3.z, 0.f), w3.z, p);
        p = fmaf(fmaxf(a3.w + q3.w, 0.f), w3.w, p);
        #pragma unroll
        for (int off = 1; off < 16; off <<= 1)
            p += __shfl_xor(p, off, 64);               // stays within jj group
        if (c == 0)
            out[(b * V_ + i) * V_ + jq * 32 + jr] =
                1.f / (1.f + __builtin_expf(-(p + bo0)));
    }
}

// ---------------------------------------------------------------------------
extern "C" void kernel_launch(void* const* d_in, const int* in_sizes, int n_in,
                              void* d_out, int out_size, void* d_ws, size_t ws_size,
                              hipStream_t stream) {
    const int*   adj   = (const int*)  d_in[0];
    const float* xf    = (const float*)d_in[1];
    const float* ea    = (const float*)d_in[2];
    const float* ec1W1 = (const float*)d_in[3];
    const float* ec1b1 = (const float*)d_in[4];
    const float* ec1W2 = (const float*)d_in[5];
    const float* ec1b2 = (const float*)d_in[6];
    const float* ec2W1 = (const float*)d_in[7];
    const float* ec2b1 = (const float*)d_in[8];
    const float* ec2W2 = (const float*)d_in[9];
    const float* ec2b2 = (const float*)d_in[10];
    const float* h3W   = (const float*)d_in[11];
    const float* h3b   = (const float*)d_in[12];
    const float* oW    = (const float*)d_in[13];
    const float* ob    = (const float*)d_in[14];
    float* out = (float*)d_out;

    const int NV = B_ * V_;                    // 1024 nodes
    float* x1 = (float*)d_ws;                  // NV*H0
    float* x2 = x1 + NV * H0_;                 // NV*H0
    float* R  = x2 + NV * H0_;                 // reuse region
    float* P  = R;                             // NV*H0
    float* Q  = R + NV * H0_;                  // NV*H0
    float* Ai = R;                             // NV*H2 (P/Q dead by then)
    float* Aj = R + NV * H2_;                  // NV*H2
    short* wsW = (short*)(R + 2 * NV * H2_);   // 40960 bf16 weights
    short* W1cT1 = wsW;
    short* W2T1  = wsW + 4096;
    short* W1cT2 = wsW + 20480;
    short* W2T2  = wsW + 24576;

    // launch 1: weight prep (160 blocks) || node hoist conv1 (512 blocks)
    pre1_fused_k<<<672, 256, 0, stream>>>(ec1W1 + 2 * C1_ * H0_, ec1W2,
                                          ec2W1 + 2 * H0_ * H0_, ec2W2, wsW,
                                          xf, ec1W1, ec1b1, P, Q);
    // conv1
    conv_mfma_k<<<NV, 256, 0, stream>>>(adj, ea, P, Q, W1cT1, W2T1, ec1b2, x1);
    // conv2
    npre2_k<H0_><<<512, 256, 0, stream>>>(x1, ec2W1, ec2b1, P, Q);
    conv_mfma_k<<<NV, 256, 0, stream>>>(adj, ea, P, Q, W1cT2, W2T2, ec2b2, x2);
    // pair scoring
    ppre2_k<<<512, 256, 0, stream>>>(x2, h3W, h3b, Ai, Aj);
    pair_out_k<<<2048, 256, 0, stream>>>(Ai, Aj, oW, ob, out);
}

// Round 9
// 208.661 us; speedup vs baseline: 1.4421x; 1.2602x over previous
//
#include <hip/hip_runtime.h>
#include <math.h>

#define B_  4
#define V_  256
#define C1_ 64
#define C2_ 32
#define H0_ 128
#define H2_ 256

typedef short bf16x8 __attribute__((ext_vector_type(8)));
typedef float f32x4  __attribute__((ext_vector_type(4)));

static __device__ __forceinline__ short f2bf(float f) {
    unsigned u = __float_as_uint(f);
    u += 0x7fffu + ((u >> 16) & 1u);          // RNE
    return (short)(u >> 16);
}

// ---------------------------------------------------------------------------
// Weight prep body: transpose + bf16-convert W1c ([32][H0]->[H0][32]) and
// W2 ([H0][H0]->[H0][H0]^T) for both conv layers.
// Layout in wsW (shorts): W1cT1[128*32] | W2T1[128*128] | W1cT2 | W2T2
// ---------------------------------------------------------------------------
static __device__ __forceinline__ void prep_body(
    int idx, const float* __restrict__ W1c1, const float* __restrict__ W21,
    const float* __restrict__ W1c2, const float* __restrict__ W22,
    short* __restrict__ wsW)
{
    if (idx < 4096) {
        int n = idx >> 5, k = idx & 31;
        wsW[idx] = f2bf(W1c1[k * H0_ + n]);
    } else if (idx < 20480) {
        int t = idx - 4096; int n = t >> 7, k = t & 127;
        wsW[idx] = f2bf(W21[k * H0_ + n]);
    } else if (idx < 24576) {
        int t = idx - 20480; int n = t >> 5, k = t & 31;
        wsW[idx] = f2bf(W1c2[k * H0_ + n]);
    } else if (idx < 40960) {
        int t = idx - 24576; int n = t >> 7, k = t & 127;
        wsW[idx] = f2bf(W22[k * H0_ + n]);
    }
}

// ---------------------------------------------------------------------------
// Node hoist for conv1 (input xf, plain rows), 2 nodes per 256-thread block.
// ---------------------------------------------------------------------------
template <int CIN>
static __device__ __forceinline__ void npre_body(
    int node0, const float* __restrict__ x, const float* __restrict__ W1,
    const float* __restrict__ b1, float* __restrict__ P, float* __restrict__ Q,
    float* __restrict__ sx2)
{
    const int tid  = threadIdx.x;
    const int half = tid >> 7;
    const int n    = tid & 127;
    const int bi   = node0 + half;
    float* sx = sx2 + half * CIN;
    if (n < CIN) sx[n] = x[bi * CIN + n];
    __syncthreads();
    float accP = b1[n], accQ = 0.f;
    #pragma unroll 4
    for (int k = 0; k < CIN; k += 4) {
        float4 xv = *reinterpret_cast<const float4*>(&sx[k]);
        float wa0 = W1[(k + 0) * H0_ + n], wb0 = W1[(CIN + k + 0) * H0_ + n];
        float wa1 = W1[(k + 1) * H0_ + n], wb1 = W1[(CIN + k + 1) * H0_ + n];
        float wa2 = W1[(k + 2) * H0_ + n], wb2 = W1[(CIN + k + 2) * H0_ + n];
        float wa3 = W1[(k + 3) * H0_ + n], wb3 = W1[(CIN + k + 3) * H0_ + n];
        accP = fmaf(xv.x, wa0 - wb0, accP);  accQ = fmaf(xv.x, wb0, accQ);
        accP = fmaf(xv.y, wa1 - wb1, accP);  accQ = fmaf(xv.y, wb1, accQ);
        accP = fmaf(xv.z, wa2 - wb2, accP);  accQ = fmaf(xv.z, wb2, accQ);
        accP = fmaf(xv.w, wa3 - wb3, accP);  accQ = fmaf(xv.w, wb3, accQ);
    }
    P[bi * H0_ + n] = accP;
    Q[bi * H0_ + n] = accQ;
}

// ---------------------------------------------------------------------------
// Fused launch 1: blocks 0..159 = weight prep; blocks 160..671 = node hoist
// for conv1 (2 nodes/block).
// ---------------------------------------------------------------------------
__global__ __launch_bounds__(256) void pre1_fused_k(
    const float* __restrict__ W1c1, const float* __restrict__ W21,
    const float* __restrict__ W1c2, const float* __restrict__ W22,
    short* __restrict__ wsW,
    const float* __restrict__ xf, const float* __restrict__ ec1W1,
    const float* __restrict__ ec1b1, float* __restrict__ P, float* __restrict__ Q)
{
    if (blockIdx.x < 160) {
        prep_body(blockIdx.x * 256 + threadIdx.x, W1c1, W21, W1c2, W22, wsW);
    } else {
        __shared__ __align__(16) float sx2[2 * C1_];
        npre_body<C1_>((blockIdx.x - 160) * 2, xf, ec1W1, ec1b1, P, Q, sx2);
    }
}

// ---------------------------------------------------------------------------
// Node hoist for conv2 reading SPLIT conv1 output xh[node*2 + s][H0]:
// stage sx[n] = fmax(half0, half1) -- same value bitwise as the unsplit max.
// 2 nodes per 256-thread block, 512 blocks.
// ---------------------------------------------------------------------------
__global__ __launch_bounds__(256) void npre2h_k(
    const float* __restrict__ xh, const float* __restrict__ W1,
    const float* __restrict__ b1, float* __restrict__ P, float* __restrict__ Q)
{
    const int tid  = threadIdx.x;
    const int half = tid >> 7;
    const int n    = tid & 127;
    const int bi   = blockIdx.x * 2 + half;
    __shared__ __align__(16) float sx2[2 * H0_];
    float* sx = sx2 + half * H0_;
    sx[n] = fmaxf(xh[(bi * 2 + 0) * H0_ + n], xh[(bi * 2 + 1) * H0_ + n]);
    __syncthreads();
    float accP = b1[n], accQ = 0.f;
    #pragma unroll 4
    for (int k = 0; k < H0_; k += 4) {
        float4 xv = *reinterpret_cast<const float4*>(&sx[k]);
        float wa0 = W1[(k + 0) * H0_ + n], wb0 = W1[(H0_ + k + 0) * H0_ + n];
        float wa1 = W1[(k + 1) * H0_ + n], wb1 = W1[(H0_ + k + 1) * H0_ + n];
        float wa2 = W1[(k + 2) * H0_ + n], wb2 = W1[(H0_ + k + 2) * H0_ + n];
        float wa3 = W1[(k + 3) * H0_ + n], wb3 = W1[(H0_ + k + 3) * H0_ + n];
        accP = fmaf(xv.x, wa0 - wb0, accP);  accQ = fmaf(xv.x, wb0, accQ);
        accP = fmaf(xv.y, wa1 - wb1, accP);  accQ = fmaf(xv.y, wb1, accQ);
        accP = fmaf(xv.z, wa2 - wb2, accP);  accQ = fmaf(xv.z, wb2, accQ);
        accP = fmaf(xv.w, wa3 - wb3, accP);  accQ = fmaf(xv.w, wb3, accQ);
    }
    P[bi * H0_ + n] = accP;
    Q[bi * H0_ + n] = accQ;
}

// ---------------------------------------------------------------------------
// EdgeConvE main, 2-WAY EDGE SPLIT: grid 2048, block = (node bi, half s).
// R8 showed VGPR=64 already permits 8 waves/SIMD; the occupancy limiter was
// the 1024-block grid (exactly 4 blocks/CU).  Splitting each node's edge
// list in half doubles the co-residency pool (8 blocks/CU: 8x18.5KB=148KB
// LDS, 64 VGPR).  Partial maxima go to outh[bi*2+s][H0]; consumers take
// fmax of the halves (bit-exact: max of maxes, all values >= 0).
// Bounds stay (256,4): R8 proved forcing 8 spills to scratch.
// ---------------------------------------------------------------------------
__global__ __launch_bounds__(256, 4) void conv_mfma_k(
    const int* __restrict__ adj, const float* __restrict__ e,
    const float* __restrict__ P, const float* __restrict__ Q,
    const short* __restrict__ W1cT, const short* __restrict__ W2T,
    const float* __restrict__ b2, float* __restrict__ outh)
{
    const int blk  = blockIdx.x;           // 2048
    const int bi   = blk >> 1;             // b*V + i
    const int sh   = blk & 1;              // which half of the edge list
    const int b    = bi >> 8;
    const int tid  = threadIdx.x;
    const int w    = tid >> 6;
    const int lane = tid & 63;
    const int l15  = lane & 15;
    const int quad = lane >> 4;

    __shared__ int s_list[V_];
    __shared__ int s_wc[4];
    __shared__ __align__(16) short s_h1[64][136];   // 272 B stride, 16B-aligned

    // ballot-based neighbor list (no atomics)
    const int av = adj[bi * V_ + tid];
    unsigned long long bm = __ballot(av > 0);
    if (lane == 0) s_wc[w] = __popcll(bm);
    __syncthreads();
    const int cnt = s_wc[0] + s_wc[1] + s_wc[2] + s_wc[3];
    if (av > 0) {
        int base = 0;
        #pragma unroll
        for (int k = 0; k < 4; ++k) if (k < w) base += s_wc[k];
        int pos = base + __popcll(bm & ((1ull << lane) - 1ull));
        s_list[pos] = tid;
    }
    __syncthreads();

    // this block's edge range
    const int h  = (cnt + 1) >> 1;
    const int lo = sh * h;
    const int hi = min(lo + h, cnt);
    float* orow = outh + blk * H0_;
    if (hi <= lo) { if (tid < H0_) orow[tid] = 0.f; return; }  // empty half

    // GEMM2 B-fragments: wave w owns N-tiles 2w, 2w+1 -> 8 frags (32 VGPR)
    bf16x8 B2[2][4];
    float bb[2], vmax[2];
    #pragma unroll
    for (int hh = 0; hh < 2; ++hh) {
        const int nt = w * 2 + hh;
        #pragma unroll
        for (int kk = 0; kk < 4; ++kk)
            B2[hh][kk] = *(const bf16x8*)(W2T + (nt * 16 + l15) * H0_ + kk * 32 + quad * 8);
        bb[hh]   = b2[nt * 16 + l15];
        vmax[hh] = 0.f;
    }
    float Pp[8];
    #pragma unroll
    for (int nt = 0; nt < 8; ++nt) Pp[nt] = P[bi * H0_ + nt * 16 + l15];

    const int row0 = w * 16;

    // prefetch first pass's e rows
    int ta0 = lo + row0 + l15; if (ta0 >= hi) ta0 = hi - 1;
    const float* er0 = e + (bi * V_ + s_list[ta0]) * C2_ + quad * 8;
    float4 e0 = *(const float4*)(er0);
    float4 e1 = *(const float4*)(er0 + 4);

    for (int t0 = lo; t0 < hi; t0 += 64) {
        const int tb = t0 + row0;

        // A-fragment for GEMM1 from prefetched e: A[m=l15][k=quad*8+j]
        bf16x8 A1;
        A1[0] = f2bf(e0.x); A1[1] = f2bf(e0.y); A1[2] = f2bf(e0.z); A1[3] = f2bf(e0.w);
        A1[4] = f2bf(e1.x); A1[5] = f2bf(e1.y); A1[6] = f2bf(e1.z); A1[7] = f2bf(e1.w);

        // issue next pass's e loads now; they retire under GEMM1+GEMM2
        {
            int tn = t0 + 64 + row0 + l15; if (tn >= hi) tn = hi - 1;
            const float* ern = e + (bi * V_ + s_list[tn]) * C2_ + quad * 8;
            e0 = *(const float4*)(ern);
            e1 = *(const float4*)(ern + 4);
        }

        // GEMM1: e @ W1c (K=32, one MFMA per N-tile)
        f32x4 acc[8];
        #pragma unroll
        for (int nt = 0; nt < 8; ++nt) {
            bf16x8 B1 = *(const bf16x8*)(W1cT + (nt * 16 + l15) * C2_ + quad * 8);
            f32x4 z = {0.f, 0.f, 0.f, 0.f};
            acc[nt] = __builtin_amdgcn_mfma_f32_16x16x32_bf16(A1, B1, z, 0, 0, 0);
        }

        // make sure previous pass's GEMM2 readers are done before overwriting
        if (t0 > lo) __syncthreads();

        // epilogue 1: + P[i] + Q[j], relu, bf16 -> LDS (rows = edge slots)
        #pragma unroll
        for (int r = 0; r < 4; ++r) {
            int t = tb + quad * 4 + r; if (t >= hi) t = hi - 1;
            const float* Qr = Q + (b * V_ + s_list[t]) * H0_ + l15;
            short* dst = &s_h1[row0 + quad * 4 + r][l15];
            #pragma unroll
            for (int nt = 0; nt < 8; ++nt) {
                float v = acc[nt][r] + Pp[nt] + Qr[nt * 16];
                dst[nt * 16] = f2bf(fmaxf(v, 0.f));
            }
        }

        __syncthreads();

        // GEMM2: h1 @ W2, N-split across waves, M = all 64 edge rows
        #pragma unroll
        for (int mt = 0; mt < 4; ++mt) {
            f32x4 a20 = {0.f,0.f,0.f,0.f}, a21 = {0.f,0.f,0.f,0.f};
            #pragma unroll
            for (int kk = 0; kk < 4; ++kk) {
                bf16x8 A2 = *(const bf16x8*)(&s_h1[mt * 16 + l15][kk * 32 + quad * 8]);
                a20 = __builtin_amdgcn_mfma_f32_16x16x32_bf16(A2, B2[0][kk], a20, 0, 0, 0);
                a21 = __builtin_amdgcn_mfma_f32_16x16x32_bf16(A2, B2[1][kk], a21, 0, 0, 0);
            }
            float m0 = fmaxf(fmaxf(a20[0], a20[1]), fmaxf(a20[2], a20[3]));
            float m1 = fmaxf(fmaxf(a21[0], a21[1]), fmaxf(a21[2], a21[3]));
            vmax[0] = fmaxf(vmax[0], fmaxf(m0 + bb[0], 0.f));
            vmax[1] = fmaxf(vmax[1], fmaxf(m1 + bb[1], 0.f));
        }
    }

    // cross-quad (rows) max, then direct write of this half's channels
    #pragma unroll
    for (int hh = 0; hh < 2; ++hh) {
        float p = vmax[hh];
        p = fmaxf(p, __shfl_xor(p, 16, 64));
        p = fmaxf(p, __shfl_xor(p, 32, 64));
        if (quad == 0) orow[(w * 2 + hh) * 16 + l15] = p;
    }
}

// ---------------------------------------------------------------------------
// Pair hoist reading SPLIT conv2 output x2h[node*2+s][H0]: stage
// s_x[n] = fmax(half0, half1).  2 nodes per block, thread n computes both
// nodes' column-n outputs sharing one W3 stream.  Bit-exact fma order.
// ---------------------------------------------------------------------------
__global__ __launch_bounds__(256) void ppre2h_k(
    const float* __restrict__ x2h, const float* __restrict__ W3,
    const float* __restrict__ b3, float* __restrict__ Ai, float* __restrict__ Aj)
{
    const int nb = blockIdx.x;         // 512 blocks, 2 nodes each
    const int n  = threadIdx.x;        // 256
    __shared__ __align__(16) float s_x[2 * H0_];
    {
        const int node = nb * 2 + (n >> 7);
        const int ch   = n & 127;
        s_x[n] = fmaxf(x2h[(node * 2 + 0) * H0_ + ch],
                       x2h[(node * 2 + 1) * H0_ + ch]);
    }
    __syncthreads();
    const float bv = b3[n];
    float aI0 = bv, aJ0 = 0.f, aI1 = bv, aJ1 = 0.f;
    #pragma unroll 4
    for (int k = 0; k < H0_; k += 4) {
        float4 x0 = *reinterpret_cast<const float4*>(&s_x[k]);
        float4 x1 = *reinterpret_cast<const float4*>(&s_x[H0_ + k]);
        float wj0 = W3[(k + 0) * H2_ + n];
        float wj1 = W3[(k + 1) * H2_ + n];
        float wj2 = W3[(k + 2) * H2_ + n];
        float wj3 = W3[(k + 3) * H2_ + n];
        float wi0 = W3[(H0_ + k + 0) * H2_ + n];
        float wi1 = W3[(H0_ + k + 1) * H2_ + n];
        float wi2 = W3[(H0_ + k + 2) * H2_ + n];
        float wi3 = W3[(H0_ + k + 3) * H2_ + n];
        aJ0 = fmaf(x0.x, wj0, aJ0); aJ0 = fmaf(x0.y, wj1, aJ0);
        aJ0 = fmaf(x0.z, wj2, aJ0); aJ0 = fmaf(x0.w, wj3, aJ0);
        aI0 = fmaf(x0.x, wi0, aI0); aI0 = fmaf(x0.y, wi1, aI0);
        aI0 = fmaf(x0.z, wi2, aI0); aI0 = fmaf(x0.w, wi3, aI0);
        aJ1 = fmaf(x1.x, wj0, aJ1); aJ1 = fmaf(x1.y, wj1, aJ1);
        aJ1 = fmaf(x1.z, wj2, aJ1); aJ1 = fmaf(x1.w, wj3, aJ1);
        aI1 = fmaf(x1.x, wi0, aI1); aI1 = fmaf(x1.y, wi1, aI1);
        aI1 = fmaf(x1.z, wi2, aI1); aI1 = fmaf(x1.w, wi3, aI1);
    }
    const int r0 = nb * 2;
    Ai[r0 * H2_ + n]       = aI0;
    Aj[r0 * H2_ + n]       = aJ0;
    Ai[(r0 + 1) * H2_ + n] = aI1;
    Aj[(r0 + 1) * H2_ + n] = aJ1;
}

// ---------------------------------------------------------------------------
// Pair output — byte-identical to R3/R6: 2048 blocks, Aj tile staged in LDS
// with float4 XOR swizzle.
// ---------------------------------------------------------------------------
__global__ __launch_bounds__(256) void pair_out_k(
    const float* __restrict__ Ai, const float* __restrict__ Aj,
    const float* __restrict__ Wo, const float* __restrict__ bo,
    float* __restrict__ out)
{
    const int blk  = blockIdx.x;                       // 2048 blocks
    const int b    = blk >> 9;
    const int ig   = (blk >> 3) & 63;
    const int jq   = blk & 7;                          // 8 tiles of 32 j
    const int i    = (ig << 2) + (threadIdx.x >> 6);
    const int lane = threadIdx.x & 63;
    const int jj   = lane >> 4;
    const int c    = lane & 15;

    __shared__ __align__(16) float4 s_aj[32 * 64];     // 32 KB, swizzled

    // cooperative stage: 32 rows x 64 float4 (coalesced; write = row-perm)
    const float4* src = (const float4*)(Aj + (b * V_ + jq * 32) * H2_);
    #pragma unroll
    for (int k = 0; k < 8; ++k) {
        int g  = threadIdx.x + k * 256;
        int jr = g >> 6, f = g & 63;
        s_aj[jr * 64 + (f ^ (jr & 7))] = src[g];
    }

    const float* ai = Ai + (b * V_ + i) * H2_ + c * 16;
    float4 a0 = *(const float4*)(ai);
    float4 a1 = *(const float4*)(ai + 4);
    float4 a2 = *(const float4*)(ai + 8);
    float4 a3 = *(const float4*)(ai + 12);
    const float* wo = Wo + c * 16;
    float4 w0 = *(const float4*)(wo);
    float4 w1 = *(const float4*)(wo + 4);
    float4 w2 = *(const float4*)(wo + 8);
    float4 w3 = *(const float4*)(wo + 12);
    const float bo0 = bo[0];

    __syncthreads();

    for (int js = 0; js < 32; js += 4) {
        const int jr = js + jj;
        const float4* arow = &s_aj[jr * 64];
        const int sw = jr & 7, f0 = c * 4;
        float4 q0 = arow[(f0 + 0) ^ sw];
        float4 q1 = arow[(f0 + 1) ^ sw];
        float4 q2 = arow[(f0 + 2) ^ sw];
        float4 q3 = arow[(f0 + 3) ^ sw];
        float p;
        p = fmaxf(a0.x + q0.x, 0.f) * w0.x;
        p = fmaf(fmaxf(a0.y + q0.y, 0.f), w0.y, p);
        p = fmaf(fmaxf(a0.z + q0.z, 0.f), w0.z, p);
        p = fmaf(fmaxf(a0.w + q0.w, 0.f), w0.w, p);
        p = fmaf(fmaxf(a1.x + q1.x, 0.f), w1.x, p);
        p = fmaf(fmaxf(a1.y + q1.y, 0.f), w1.y, p);
        p = fmaf(fmaxf(a1.z + q1.z, 0.f), w1.z, p);
        p = fmaf(fmaxf(a1.w + q1.w, 0.f), w1.w, p);
        p = fmaf(fmaxf(a2.x + q2.x, 0.f), w2.x, p);
        p = fmaf(fmaxf(a2.y + q2.y, 0.f), w2.y, p);
        p = fmaf(fmaxf(a2.z + q2.z, 0.f), w2.z, p);
        p = fmaf(fmaxf(a2.w + q2.w, 0.f), w2.w, p);
        p = fmaf(fmaxf(a3.x + q3.x, 0.f), w3.x, p);
        p = fmaf(fmaxf(a3.y + q3.y, 0.f), w3.y, p);
        p = fmaf(fmaxf(a3.z + q3.z, 0.f), w3.z, p);
        p = fmaf(fmaxf(a3.w + q3.w, 0.f), w3.w, p);
        #pragma unroll
        for (int off = 1; off < 16; off <<= 1)
            p += __shfl_xor(p, off, 64);               // stays within jj group
        if (c == 0)
            out[(b * V_ + i) * V_ + jq * 32 + jr] =
                1.f / (1.f + __builtin_expf(-(p + bo0)));
    }
}

// ---------------------------------------------------------------------------
extern "C" void kernel_launch(void* const* d_in, const int* in_sizes, int n_in,
                              void* d_out, int out_size, void* d_ws, size_t ws_size,
                              hipStream_t stream) {
    const int*   adj   = (const int*)  d_in[0];
    const float* xf    = (const float*)d_in[1];
    const float* ea    = (const float*)d_in[2];
    const float* ec1W1 = (const float*)d_in[3];
    const float* ec1b1 = (const float*)d_in[4];
    const float* ec1W2 = (const float*)d_in[5];
    const float* ec1b2 = (const float*)d_in[6];
    const float* ec2W1 = (const float*)d_in[7];
    const float* ec2b1 = (const float*)d_in[8];
    const float* ec2W2 = (const float*)d_in[9];
    const float* ec2b2 = (const float*)d_in[10];
    const float* h3W   = (const float*)d_in[11];
    const float* h3b   = (const float*)d_in[12];
    const float* oW    = (const float*)d_in[13];
    const float* ob    = (const float*)d_in[14];
    float* out = (float*)d_out;

    const int NV = B_ * V_;                    // 1024 nodes
    float* x1h = (float*)d_ws;                 // NV*2*H0 (split conv1 out)
    float* x2h = x1h + NV * 2 * H0_;           // NV*2*H0 (split conv2 out)
    float* P   = x2h + NV * 2 * H0_;           // NV*H0
    float* Q   = P  + NV * H0_;                // NV*H0
    float* Ai  = Q  + NV * H0_;                // NV*H2
    float* Aj  = Ai + NV * H2_;                // NV*H2
    short* wsW = (short*)(Aj + NV * H2_);      // 40960 bf16 weights
    short* W1cT1 = wsW;
    short* W2T1  = wsW + 4096;
    short* W1cT2 = wsW + 20480;
    short* W2T2  = wsW + 24576;

    // launch 1: weight prep (160 blocks) || node hoist conv1 (512 blocks)
    pre1_fused_k<<<672, 256, 0, stream>>>(ec1W1 + 2 * C1_ * H0_, ec1W2,
                                          ec2W1 + 2 * H0_ * H0_, ec2W2, wsW,
                                          xf, ec1W1, ec1b1, P, Q);
    // conv1 (2-way edge split, 2048 blocks)
    conv_mfma_k<<<2 * NV, 256, 0, stream>>>(adj, ea, P, Q, W1cT1, W2T1,
                                            ec1b2, x1h);
    // conv2 hoist (max of halves) then conv2 (split)
    npre2h_k<<<512, 256, 0, stream>>>(x1h, ec2W1, ec2b1, P, Q);
    conv_mfma_k<<<2 * NV, 256, 0, stream>>>(adj, ea, P, Q, W1cT2, W2T2,
                                            ec2b2, x2h);
    // pair scoring (max of halves)
    ppre2h_k<<<512, 256, 0, stream>>>(x2h, h3W, h3b, Ai, Aj);
    pair_out_k<<<2048, 256, 0, stream>>>(Ai, Aj, oW, ob, out);
}

// Round 10
// 185.404 us; speedup vs baseline: 1.6230x; 1.1254x over previous
//
#include <hip/hip_runtime.h>
#include <math.h>

#define B_  4
#define V_  256
#define C1_ 64
#define C2_ 32
#define H0_ 128
#define H2_ 256

typedef short bf16x8 __attribute__((ext_vector_type(8)));
typedef float f32x4  __attribute__((ext_vector_type(4)));

static __device__ __forceinline__ short f2bf(float f) {
    unsigned u = __float_as_uint(f);
    u += 0x7fffu + ((u >> 16) & 1u);          // RNE
    return (short)(u >> 16);
}

// ---------------------------------------------------------------------------
// Weight prep body: transpose + bf16-convert W1c ([32][H0]->[H0][32]) and
// W2 ([H0][H0]->[H0][H0]^T) for both conv layers.
// Layout in wsW (shorts): W1cT1[128*32] | W2T1[128*128] | W1cT2 | W2T2
// ---------------------------------------------------------------------------
static __device__ __forceinline__ void prep_body(
    int idx, const float* __restrict__ W1c1, const float* __restrict__ W21,
    const float* __restrict__ W1c2, const float* __restrict__ W22,
    short* __restrict__ wsW)
{
    if (idx < 4096) {
        int n = idx >> 5, k = idx & 31;
        wsW[idx] = f2bf(W1c1[k * H0_ + n]);
    } else if (idx < 20480) {
        int t = idx - 4096; int n = t >> 7, k = t & 127;
        wsW[idx] = f2bf(W21[k * H0_ + n]);
    } else if (idx < 24576) {
        int t = idx - 20480; int n = t >> 5, k = t & 31;
        wsW[idx] = f2bf(W1c2[k * H0_ + n]);
    } else if (idx < 40960) {
        int t = idx - 24576; int n = t >> 7, k = t & 127;
        wsW[idx] = f2bf(W22[k * H0_ + n]);
    }
}

// ---------------------------------------------------------------------------
// Node hoist, 2 nodes per 256-thread block (conv1 hoist from xf).
// ---------------------------------------------------------------------------
template <int CIN>
static __device__ __forceinline__ void npre_body(
    int node0, const float* __restrict__ x, const float* __restrict__ W1,
    const float* __restrict__ b1, float* __restrict__ P, float* __restrict__ Q,
    float* __restrict__ sx2)
{
    const int tid  = threadIdx.x;
    const int half = tid >> 7;
    const int n    = tid & 127;
    const int bi   = node0 + half;
    float* sx = sx2 + half * CIN;
    if (n < CIN) sx[n] = x[bi * CIN + n];
    __syncthreads();
    float accP = b1[n], accQ = 0.f;
    #pragma unroll 4
    for (int k = 0; k < CIN; k += 4) {
        float4 xv = *reinterpret_cast<const float4*>(&sx[k]);
        float wa0 = W1[(k + 0) * H0_ + n], wb0 = W1[(CIN + k + 0) * H0_ + n];
        float wa1 = W1[(k + 1) * H0_ + n], wb1 = W1[(CIN + k + 1) * H0_ + n];
        float wa2 = W1[(k + 2) * H0_ + n], wb2 = W1[(CIN + k + 2) * H0_ + n];
        float wa3 = W1[(k + 3) * H0_ + n], wb3 = W1[(CIN + k + 3) * H0_ + n];
        accP = fmaf(xv.x, wa0 - wb0, accP);  accQ = fmaf(xv.x, wb0, accQ);
        accP = fmaf(xv.y, wa1 - wb1, accP);  accQ = fmaf(xv.y, wb1, accQ);
        accP = fmaf(xv.z, wa2 - wb2, accP);  accQ = fmaf(xv.z, wb2, accQ);
        accP = fmaf(xv.w, wa3 - wb3, accP);  accQ = fmaf(xv.w, wb3, accQ);
    }
    P[bi * H0_ + n] = accP;
    Q[bi * H0_ + n] = accQ;
}

// ---------------------------------------------------------------------------
// Fused launch 1: blocks 0..159 = weight prep; 160..671 = node hoist conv1;
// 672..4767 = e fp32->bf16 pre-conversion (8.4M elems, 8/thread).  All three
// parts are independent.  e16 holds EXACTLY f2bf(e[g]) -> conv's A1 fragment
// registers are bit-identical to the in-kernel conversion they replace.
// ---------------------------------------------------------------------------
__global__ __launch_bounds__(256) void pre1_fused_k(
    const float* __restrict__ W1c1, const float* __restrict__ W21,
    const float* __restrict__ W1c2, const float* __restrict__ W22,
    short* __restrict__ wsW,
    const float* __restrict__ xf, const float* __restrict__ ec1W1,
    const float* __restrict__ ec1b1, float* __restrict__ P, float* __restrict__ Q,
    const float* __restrict__ e, short* __restrict__ e16)
{
    if (blockIdx.x < 160) {
        prep_body(blockIdx.x * 256 + threadIdx.x, W1c1, W21, W1c2, W22, wsW);
    } else if (blockIdx.x < 672) {
        __shared__ __align__(16) float sx2[2 * C1_];
        npre_body<C1_>((blockIdx.x - 160) * 2, xf, ec1W1, ec1b1, P, Q, sx2);
    } else {
        const int g = (blockIdx.x - 672) * 2048 + threadIdx.x * 8;
        float4 a = *(const float4*)(e + g);
        float4 b = *(const float4*)(e + g + 4);
        bf16x8 v;
        v[0] = f2bf(a.x); v[1] = f2bf(a.y); v[2] = f2bf(a.z); v[3] = f2bf(a.w);
        v[4] = f2bf(b.x); v[5] = f2bf(b.y); v[6] = f2bf(b.z); v[7] = f2bf(b.w);
        *(bf16x8*)(e16 + g) = v;
    }
}

// standalone 2-node node_pre for conv2 (CIN=128), grid 512
template <int CIN>
__global__ __launch_bounds__(256) void npre2_k(
    const float* __restrict__ x, const float* __restrict__ W1,
    const float* __restrict__ b1, float* __restrict__ P, float* __restrict__ Q)
{
    __shared__ __align__(16) float sx2[2 * CIN];
    npre_body<CIN>(blockIdx.x * 2, x, W1, b1, P, Q, sx2);
}

// ---------------------------------------------------------------------------
// EdgeConvE main — R6 structure (best known: 1024 blocks, 4 blocks/CU,
// ballot list, N-split GEMM2), with e pre-converted to bf16: the per-pass
// prefetch is ONE 16 B load (was 2x float4 + 16 cvt ops), A1 bit-identical.
// ---------------------------------------------------------------------------
__global__ __launch_bounds__(256, 4) void conv_mfma_k(
    const int* __restrict__ adj, const short* __restrict__ e16,
    const float* __restrict__ P, const float* __restrict__ Q,
    const short* __restrict__ W1cT, const short* __restrict__ W2T,
    const float* __restrict__ b2, float* __restrict__ out)
{
    const int bi   = blockIdx.x;           // b*V + i
    const int b    = bi >> 8;
    const int tid  = threadIdx.x;
    const int w    = tid >> 6;
    const int lane = tid & 63;
    const int l15  = lane & 15;
    const int quad = lane >> 4;

    __shared__ int s_list[V_];
    __shared__ int s_wc[4];
    __shared__ __align__(16) short s_h1[64][136];   // 272 B stride, 16B-aligned

    // ballot-based neighbor list (no atomics)
    const int av = adj[bi * V_ + tid];
    unsigned long long bm = __ballot(av > 0);
    if (lane == 0) s_wc[w] = __popcll(bm);
    __syncthreads();
    const int cnt = s_wc[0] + s_wc[1] + s_wc[2] + s_wc[3];
    if (av > 0) {
        int base = 0;
        #pragma unroll
        for (int k = 0; k < 4; ++k) if (k < w) base += s_wc[k];
        int pos = base + __popcll(bm & ((1ull << lane) - 1ull));
        s_list[pos] = tid;
    }
    __syncthreads();
    if (cnt == 0) { if (tid < H0_) out[bi * H0_ + tid] = 0.f; return; }

    // GEMM2 B-fragments: wave w owns N-tiles 2w, 2w+1 -> 8 frags (32 VGPR)
    bf16x8 B2[2][4];
    float bb[2], vmax[2];
    #pragma unroll
    for (int h = 0; h < 2; ++h) {
        const int nt = w * 2 + h;
        #pragma unroll
        for (int kk = 0; kk < 4; ++kk)
            B2[h][kk] = *(const bf16x8*)(W2T + (nt * 16 + l15) * H0_ + kk * 32 + quad * 8);
        bb[h]   = b2[nt * 16 + l15];
        vmax[h] = 0.f;
    }
    float Pp[8];
    #pragma unroll
    for (int nt = 0; nt < 8; ++nt) Pp[nt] = P[bi * H0_ + nt * 16 + l15];

    const int row0 = w * 16;

    // prefetch first pass's e row fragment (16 B, bf16)
    int ta0 = row0 + l15; if (ta0 >= cnt) ta0 = cnt - 1;
    bf16x8 eA = *(const bf16x8*)(e16 + (bi * V_ + s_list[ta0]) * C2_ + quad * 8);

    for (int t0 = 0; t0 < cnt; t0 += 64) {
        const int tb = t0 + row0;

        const bf16x8 A1 = eA;

        // issue next pass's e load now; it retires under GEMM1+GEMM2
        {
            int tn = t0 + 64 + row0 + l15; if (tn >= cnt) tn = cnt - 1;
            eA = *(const bf16x8*)(e16 + (bi * V_ + s_list[tn]) * C2_ + quad * 8);
        }

        // GEMM1: e @ W1c (K=32, one MFMA per N-tile; B1 from L1-resident global)
        f32x4 acc[8];
        #pragma unroll
        for (int nt = 0; nt < 8; ++nt) {
            bf16x8 B1 = *(const bf16x8*)(W1cT + (nt * 16 + l15) * C2_ + quad * 8);
            f32x4 z = {0.f, 0.f, 0.f, 0.f};
            acc[nt] = __builtin_amdgcn_mfma_f32_16x16x32_bf16(A1, B1, z, 0, 0, 0);
        }

        // make sure previous pass's GEMM2 readers are done before overwriting
        if (t0 > 0) __syncthreads();

        // epilogue 1: + P[i] + Q[j], relu, bf16 -> LDS (rows = edge slots)
        #pragma unroll
        for (int r = 0; r < 4; ++r) {
            int t = tb + quad * 4 + r; if (t >= cnt) t = cnt - 1;
            const float* Qr = Q + (b * V_ + s_list[t]) * H0_ + l15;
            short* dst = &s_h1[row0 + quad * 4 + r][l15];
            #pragma unroll
            for (int nt = 0; nt < 8; ++nt) {
                float v = acc[nt][r] + Pp[nt] + Qr[nt * 16];
                dst[nt * 16] = f2bf(fmaxf(v, 0.f));
            }
        }

        __syncthreads();

        // GEMM2: h1 @ W2, N-split across waves, M = all 64 edge rows
        #pragma unroll
        for (int mt = 0; mt < 4; ++mt) {
            f32x4 a20 = {0.f,0.f,0.f,0.f}, a21 = {0.f,0.f,0.f,0.f};
            #pragma unroll
            for (int kk = 0; kk < 4; ++kk) {
                bf16x8 A2 = *(const bf16x8*)(&s_h1[mt * 16 + l15][kk * 32 + quad * 8]);
                a20 = __builtin_amdgcn_mfma_f32_16x16x32_bf16(A2, B2[0][kk], a20, 0, 0, 0);
                a21 = __builtin_amdgcn_mfma_f32_16x16x32_bf16(A2, B2[1][kk], a21, 0, 0, 0);
            }
            float m0 = fmaxf(fmaxf(a20[0], a20[1]), fmaxf(a20[2], a20[3]));
            float m1 = fmaxf(fmaxf(a21[0], a21[1]), fmaxf(a21[2], a21[3]));
            vmax[0] = fmaxf(vmax[0], fmaxf(m0 + bb[0], 0.f));
            vmax[1] = fmaxf(vmax[1], fmaxf(m1 + bb[1], 0.f));
        }
    }

    // cross-quad (rows) max, then direct write of this wave's own channels
    #pragma unroll
    for (int h = 0; h < 2; ++h) {
        float p = vmax[h];
        p = fmaxf(p, __shfl_xor(p, 16, 64));
        p = fmaxf(p, __shfl_xor(p, 32, 64));
        if (quad == 0) out[bi * H0_ + (w * 2 + h) * 16 + l15] = p;
    }
}

// ---------------------------------------------------------------------------
// Pair hoist, 2 nodes per 256-thread block: thread n computes BOTH nodes'
// column-n outputs, sharing one W3 stream.  Bit-exact per-node fma order.
// ---------------------------------------------------------------------------
__global__ __launch_bounds__(256) void ppre2_k(
    const float* __restrict__ x2, const float* __restrict__ W3,
    const float* __restrict__ b3, float* __restrict__ Ai, float* __restrict__ Aj)
{
    const int nb = blockIdx.x;         // 512 blocks, 2 nodes each
    const int n  = threadIdx.x;        // 256
    __shared__ __align__(16) float s_x[2 * H0_];
    s_x[n] = x2[nb * 2 * H0_ + n];
    __syncthreads();
    const float bv = b3[n];
    float aI0 = bv, aJ0 = 0.f, aI1 = bv, aJ1 = 0.f;
    #pragma unroll 4
    for (int k = 0; k < H0_; k += 4) {
        float4 x0 = *reinterpret_cast<const float4*>(&s_x[k]);
        float4 x1 = *reinterpret_cast<const float4*>(&s_x[H0_ + k]);
        float wj0 = W3[(k + 0) * H2_ + n];
        float wj1 = W3[(k + 1) * H2_ + n];
        float wj2 = W3[(k + 2) * H2_ + n];
        float wj3 = W3[(k + 3) * H2_ + n];
        float wi0 = W3[(H0_ + k + 0) * H2_ + n];
        float wi1 = W3[(H0_ + k + 1) * H2_ + n];
        float wi2 = W3[(H0_ + k + 2) * H2_ + n];
        float wi3 = W3[(H0_ + k + 3) * H2_ + n];
        aJ0 = fmaf(x0.x, wj0, aJ0); aJ0 = fmaf(x0.y, wj1, aJ0);
        aJ0 = fmaf(x0.z, wj2, aJ0); aJ0 = fmaf(x0.w, wj3, aJ0);
        aI0 = fmaf(x0.x, wi0, aI0); aI0 = fmaf(x0.y, wi1, aI0);
        aI0 = fmaf(x0.z, wi2, aI0); aI0 = fmaf(x0.w, wi3, aI0);
        aJ1 = fmaf(x1.x, wj0, aJ1); aJ1 = fmaf(x1.y, wj1, aJ1);
        aJ1 = fmaf(x1.z, wj2, aJ1); aJ1 = fmaf(x1.w, wj3, aJ1);
        aI1 = fmaf(x1.x, wi0, aI1); aI1 = fmaf(x1.y, wi1, aI1);
        aI1 = fmaf(x1.z, wi2, aI1); aI1 = fmaf(x1.w, wi3, aI1);
    }
    const int r0 = nb * 2;
    Ai[r0 * H2_ + n]       = aI0;
    Aj[r0 * H2_ + n]       = aJ0;
    Ai[(r0 + 1) * H2_ + n] = aI1;
    Aj[(r0 + 1) * H2_ + n] = aJ1;
}

// ---------------------------------------------------------------------------
// Pair output — byte-identical to R3/R6: 2048 blocks, Aj tile staged in LDS
// with float4 XOR swizzle.
// ---------------------------------------------------------------------------
__global__ __launch_bounds__(256) void pair_out_k(
    const float* __restrict__ Ai, const float* __restrict__ Aj,
    const float* __restrict__ Wo, const float* __restrict__ bo,
    float* __restrict__ out)
{
    const int blk  = blockIdx.x;                       // 2048 blocks
    const int b    = blk >> 9;
    const int ig   = (blk >> 3) & 63;
    const int jq   = blk & 7;                          // 8 tiles of 32 j
    const int i    = (ig << 2) + (threadIdx.x >> 6);
    const int lane = threadIdx.x & 63;
    const int jj   = lane >> 4;
    const int c    = lane & 15;

    __shared__ __align__(16) float4 s_aj[32 * 64];     // 32 KB, swizzled

    // cooperative stage: 32 rows x 64 float4 (coalesced; write = row-perm)
    const float4* src = (const float4*)(Aj + (b * V_ + jq * 32) * H2_);
    #pragma unroll
    for (int k = 0; k < 8; ++k) {
        int g  = threadIdx.x + k * 256;
        int jr = g >> 6, f = g & 63;
        s_aj[jr * 64 + (f ^ (jr & 7))] = src[g];
    }

    const float* ai = Ai + (b * V_ + i) * H2_ + c * 16;
    float4 a0 = *(const float4*)(ai);
    float4 a1 = *(const float4*)(ai + 4);
    float4 a2 = *(const float4*)(ai + 8);
    float4 a3 = *(const float4*)(ai + 12);
    const float* wo = Wo + c * 16;
    float4 w0 = *(const float4*)(wo);
    float4 w1 = *(const float4*)(wo + 4);
    float4 w2 = *(const float4*)(wo + 8);
    float4 w3 = *(const float4*)(wo + 12);
    const float bo0 = bo[0];

    __syncthreads();

    for (int js = 0; js < 32; js += 4) {
        const int jr = js + jj;
        const float4* arow = &s_aj[jr * 64];
        const int sw = jr & 7, f0 = c * 4;
        float4 q0 = arow[(f0 + 0) ^ sw];
        float4 q1 = arow[(f0 + 1) ^ sw];
        float4 q2 = arow[(f0 + 2) ^ sw];
        float4 q3 = arow[(f0 + 3) ^ sw];
        float p;
        p = fmaxf(a0.x + q0.x, 0.f) * w0.x;
        p = fmaf(fmaxf(a0.y + q0.y, 0.f), w0.y, p);
        p = fmaf(fmaxf(a0.z + q0.z, 0.f), w0.z, p);
        p = fmaf(fmaxf(a0.w + q0.w, 0.f), w0.w, p);
        p = fmaf(fmaxf(a1.x + q1.x, 0.f), w1.x, p);
        p = fmaf(fmaxf(a1.y + q1.y, 0.f), w1.y, p);
        p = fmaf(fmaxf(a1.z + q1.z, 0.f), w1.z, p);
        p = fmaf(fmaxf(a1.w + q1.w, 0.f), w1.w, p);
        p = fmaf(fmaxf(a2.x + q2.x, 0.f), w2.x, p);
        p = fmaf(fmaxf(a2.y + q2.y, 0.f), w2.y, p);
        p = fmaf(fmaxf(a2.z + q2.z, 0.f), w2.z, p);
        p = fmaf(fmaxf(a2.w + q2.w, 0.f), w2.w, p);
        p = fmaf(fmaxf(a3.x + q3.x, 0.f), w3.x, p);
        p = fmaf(fmaxf(a3.y + q3.y, 0.f), w3.y, p);
        p = fmaf(fmaxf(a3.z + q3.z, 0.f), w3.z, p);
        p = fmaf(fmaxf(a3.w + q3.w, 0.f), w3.w, p);
        #pragma unroll
        for (int off = 1; off < 16; off <<= 1)
            p += __shfl_xor(p, off, 64);               // stays within jj group
        if (c == 0)
            out[(b * V_ + i) * V_ + jq * 32 + jr] =
                1.f / (1.f + __builtin_expf(-(p + bo0)));
    }
}

// ---------------------------------------------------------------------------
extern "C" void kernel_launch(void* const* d_in, const int* in_sizes, int n_in,
                              void* d_out, int out_size, void* d_ws, size_t ws_size,
                              hipStream_t stream) {
    const int*   adj   = (const int*)  d_in[0];
    const float* xf    = (const float*)d_in[1];
    const float* ea    = (const float*)d_in[2];
    const float* ec1W1 = (const float*)d_in[3];
    const float* ec1b1 = (const float*)d_in[4];
    const float* ec1W2 = (const float*)d_in[5];
    const float* ec1b2 = (const float*)d_in[6];
    const float* ec2W1 = (const float*)d_in[7];
    const float* ec2b1 = (const float*)d_in[8];
    const float* ec2W2 = (const float*)d_in[9];
    const float* ec2b2 = (const float*)d_in[10];
    const float* h3W   = (const float*)d_in[11];
    const float* h3b   = (const float*)d_in[12];
    const float* oW    = (const float*)d_in[13];
    const float* ob    = (const float*)d_in[14];
    float* out = (float*)d_out;

    const int NV = B_ * V_;                    // 1024 nodes
    const int NE = B_ * V_ * V_ * C2_;         // 8.4M e elements
    short* e16 = (short*)d_ws;                 // NE bf16 (16.75 MB)
    float* x1  = (float*)(e16 + NE);           // NV*H0
    float* x2  = x1 + NV * H0_;                // NV*H0
    float* R   = x2 + NV * H0_;                // reuse region
    float* P   = R;                            // NV*H0
    float* Q   = R + NV * H0_;                 // NV*H0
    float* Ai  = R;                            // NV*H2 (P/Q dead by then)
    float* Aj  = R + NV * H2_;                 // NV*H2
    short* wsW = (short*)(R + 2 * NV * H2_);   // 40960 bf16 weights
    short* W1cT1 = wsW;
    short* W2T1  = wsW + 4096;
    short* W1cT2 = wsW + 20480;
    short* W2T2  = wsW + 24576;

    // launch 1: weight prep || node hoist conv1 || e bf16 conversion
    pre1_fused_k<<<4768, 256, 0, stream>>>(ec1W1 + 2 * C1_ * H0_, ec1W2,
                                           ec2W1 + 2 * H0_ * H0_, ec2W2, wsW,
                                           xf, ec1W1, ec1b1, P, Q, ea, e16);
    // conv1
    conv_mfma_k<<<NV, 256, 0, stream>>>(adj, e16, P, Q, W1cT1, W2T1, ec1b2, x1);
    // conv2
    npre2_k<H0_><<<512, 256, 0, stream>>>(x1, ec2W1, ec2b1, P, Q);
    conv_mfma_k<<<NV, 256, 0, stream>>>(adj, e16, P, Q, W1cT2, W2T2, ec2b2, x2);
    // pair scoring
    ppre2_k<<<512, 256, 0, stream>>>(x2, h3W, h3b, Ai, Aj);
    pair_out_k<<<2048, 256, 0, stream>>>(Ai, Aj, oW, ob, out);
}